// Round 13
// baseline (145.653 us; speedup 1.0000x reference)
//
#include <hip/hip_runtime.h>

// HausdorffLoss (average): B=8, N=M=4096, C=128, fp32 in/out.
// R18 (resubmit; infra "container failed twice" — no result last round).
// Fused convert-in-kernel; prep_kernel ELIMINATED. Budget audit across
// R13-R17: fill 44us (fixed harness poison) + prep 10-15us (R16/17 prep
// even worse: fragment-order stores are 64 scattered 16B chunks/instr) +
// mfma ~35-40 + reduce ~2 + gaps. Three mfma-internal rounds were neutral
// in total because prep regressions ate the gains. Fix the biggest
// unattacked block: fold the fp32->bf16 conversion INTO the mfma kernel.
//   - A: block loads its 256 rows' frags DIRECT from fp32 S1 (32B/lane,
//     one-time, L3-absorbed), converts in-reg; row norms via in-lane
//     sum-sq + shfl_xor(16,32) + 1KB LDS redistribute. No swizzle needed
//     (it only existed for the workspace round-trip).
//   - B: per 64-col tile, coalesced fp32 loads (thread=col x 32k chunk,
//     wave-contiguous 8KB), col norms via shfl_xor(1,2), convert,
//     ds_write_b128 into R15's proven swizzled LDS layout (reads
//     conflict-free). Loads issued BEFORE the MFMA section (T14 split);
//     writes land before the end-of-iter barrier.
// Keeps: e-trick (acc init = ha+hb, min d2 = -2 max e), LDS atomic
// col-max (fire-and-forget, monotone uint keys), direct rowpart stores,
// 2-dispatch plan (fused + reduce). ws use drops to 2.5 MB.
// Fill note: harness re-poisons 256MiB ws (~44us/iter) - uncontrollable.
#define B_ 8
#define N_ 4096
#define M_ 4096
#define C_ 128
#define BN_ (B_ * N_)
#define BM_ (B_ * M_)

typedef __attribute__((ext_vector_type(8))) short bf16x8;    // MFMA A/B frag
typedef __attribute__((ext_vector_type(4))) float floatx4;   // MFMA C/D frag
typedef __attribute__((ext_vector_type(8))) unsigned short ushort8;

// fp32 -> bf16 round-to-nearest-even
__device__ __forceinline__ unsigned short f2bf(float x) {
    unsigned int u = __float_as_uint(x);
    u += 0x7FFFu + ((u >> 16) & 1u);
    return (unsigned short)(u >> 16);
}

// pack 8 f32 (two float4) -> bf16x8
__device__ __forceinline__ bf16x8 pack8(float4 a, float4 b) {
    ushort8 o;
    o[0] = f2bf(a.x); o[1] = f2bf(a.y); o[2] = f2bf(a.z); o[3] = f2bf(a.w);
    o[4] = f2bf(b.x); o[5] = f2bf(b.y); o[6] = f2bf(b.z); o[7] = f2bf(b.w);
    return *(bf16x8*)&o;
}

// monotone float->uint order map (works for mixed signs, no NaN inputs)
__device__ __forceinline__ unsigned fkey(float f) {
    unsigned u = __float_as_uint(f);
    return u ^ (unsigned)(((int)u >> 31) | 0x80000000);
}
__device__ __forceinline__ float funkey(unsigned k) {
    unsigned u = (k & 0x80000000u) ? (k ^ 0x80000000u) : ~k;
    return __uint_as_float(u);
}

// ---------------------------------------------------------------------------
// Fused main: grid (N/256, M/1024, B), 256 threads. 4 waves; wave = its 64
// rows x all 64 cols of each tile. Converts fp32->bf16 inline.
// LDS: 32KB B staging + 16KB colmax keys + bhalf 512B + ascr 1KB ~= 50KB.
// ---------------------------------------------------------------------------
__global__ __launch_bounds__(256, 2) void hausdorff_fused(
    const float* __restrict__ S1, const float* __restrict__ S2,
    float* __restrict__ rowpart, float* __restrict__ colpart,
    float* __restrict__ out) {

    __shared__ unsigned short B_lds[2][64 * 128];   // 2 x 16 KB
    __shared__ unsigned int colmax_u[1024][4];      // 16 KB keys [col][quad]
    __shared__ float bhalf_t[2][64];                // per-tile -0.5*||b||^2
    __shared__ float ascr[256];                     // row-norm redistribute

    const int b     = blockIdx.z;
    const int x     = blockIdx.x;
    const int panel = blockIdx.y;                   // cols panel*1024 ..
    const int row0  = x * 256;
    const int tid   = threadIdx.x;
    const int lane  = tid & 63;
    const int w     = tid >> 6;
    const int lm    = lane & 15;
    const int quad  = lane >> 4;
    const int wrow  = w * 64;                       // wave's 64-row slice

    if (x == 0 && panel == 0 && tid == 0) out[b] = 0.f;

    // init colmax keys to 0 (== -inf under the order map)
    {
        uint4 z; z.x = z.y = z.z = z.w = 0u;
        unsigned int* cm = &colmax_u[0][0];
        #pragma unroll
        for (int k = 0; k < 4; ++k)
            *(uint4*)&cm[tid * 16 + k * 4] = z;
    }

    // ---- A phase: fp32 frags -> bf16 regs + row norms (one-time) --------
    const float* As = S1 + ((size_t)b * N_ + row0 + wrow) * C_;
    bf16x8 af[4][4];
    #pragma unroll
    for (int i = 0; i < 4; ++i) {
        float ss = 0.f;
        #pragma unroll
        for (int c = 0; c < 4; ++c) {
            // frag (i,c): row wrow+16i+lm, k = c*32 + quad*8 .. +7
            const float* p = As + (size_t)(16 * i + lm) * C_ + c * 32 + quad * 8;
            float4 u0 = *(const float4*)p;
            float4 u1 = *(const float4*)(p + 4);
            ss += u0.x*u0.x + u0.y*u0.y + u0.z*u0.z + u0.w*u0.w
                + u1.x*u1.x + u1.y*u1.y + u1.z*u1.z + u1.w*u1.w;
            af[i][c] = pack8(u0, u1);
        }
        // sum across the 4 quads sharing lm -> full 128-k norm of row 16i+lm
        ss += __shfl_xor(ss, 16, 64);
        ss += __shfl_xor(ss, 32, 64);
        if (quad == 0) ascr[wrow + 16 * i + lm] = -0.5f * ss;
    }

    // ---- B tile staging helper (fp32 -> bf16 LDS, swizzled) -------------
    const float* Bs = S2 + ((size_t)b * M_ + (size_t)panel * 1024) * C_;
    const int scol = tid >> 2;          // 0..63 tile col
    const int sk4  = tid & 3;           // k-chunk selector (32 f32 each)

    // loads for a tile (issued early), conversion+write done separately
#define STAGE_LOAD(q_, it_)                                                   \
    do {                                                                      \
        const float* sp_ = Bs + (size_t)((it_) * 64 + scol) * C_ + sk4 * 32;  \
        _Pragma("unroll")                                                     \
        for (int jj_ = 0; jj_ < 8; ++jj_)                                     \
            q_[jj_] = *(const float4*)(sp_ + jj_ * 4);                        \
    } while (0)

#define STAGE_WRITE(q_, buf_)                                                 \
    do {                                                                      \
        float ss_ = 0.f;                                                      \
        _Pragma("unroll")                                                     \
        for (int jj_ = 0; jj_ < 8; ++jj_)                                     \
            ss_ += q_[jj_].x*q_[jj_].x + q_[jj_].y*q_[jj_].y                  \
                 + q_[jj_].z*q_[jj_].z + q_[jj_].w*q_[jj_].w;                 \
        ss_ += __shfl_xor(ss_, 1, 64);                                        \
        ss_ += __shfl_xor(ss_, 2, 64);                                        \
        if (sk4 == 0) bhalf_t[buf_][scol] = -0.5f * ss_;                      \
        _Pragma("unroll")                                                     \
        for (int jj_ = 0; jj_ < 4; ++jj_) {                                   \
            bf16x8 o_ = pack8(q_[2 * jj_], q_[2 * jj_ + 1]);                  \
            const int g_ = sk4 * 4 + jj_;                                     \
            *(bf16x8*)&B_lds[buf_][scol * 128 + ((g_ ^ (scol & 15)) * 8)] = o_; \
        }                                                                     \
    } while (0)

    // stage tile 0 into buf 0
    {
        float4 q[8];
        STAGE_LOAD(q, 0);
        STAGE_WRITE(q, 0);
    }

    __syncthreads();   // ascr + colmax init + tile0 staged

    // ha in acc layout: rows wrow + 16i + 4*quad + r
    float ha[16];
    #pragma unroll
    for (int i = 0; i < 4; ++i) {
        float4 t = *(const float4*)&ascr[wrow + 16 * i + 4 * quad];
        ha[4*i+0] = t.x; ha[4*i+1] = t.y; ha[4*i+2] = t.z; ha[4*i+3] = t.w;
    }

    float rv[16];                                   // running e-max per row
    #pragma unroll
    for (int v = 0; v < 16; ++v) rv[v] = -1e30f;

    for (int it = 0; it < 16; ++it) {
        const int cur = it & 1;

        float4 q[8];
        if (it < 15) STAGE_LOAD(q, it + 1);   // issue early; hide under MFMA

        float hb[4];
        #pragma unroll
        for (int j = 0; j < 4; ++j)
            hb[j] = bhalf_t[cur][16 * j + lm];

        // acc init = ha + hb  ->  acc accumulates to  inner - (sa+sb)/2
        floatx4 acc[4][4];
        #pragma unroll
        for (int i = 0; i < 4; ++i)
            #pragma unroll
            for (int j = 0; j < 4; ++j)
                #pragma unroll
                for (int r = 0; r < 4; ++r)
                    acc[i][j][r] = ha[4 * i + r] + hb[j];

        // two j-halves of LDS frag reads + MFMA (R15's proven layout)
        #pragma unroll
        for (int h = 0; h < 2; ++h) {
            bf16x8 bfr[2][4];
            #pragma unroll
            for (int j2 = 0; j2 < 2; ++j2)
                #pragma unroll
                for (int c = 0; c < 4; ++c)
                    bfr[j2][c] = *(const bf16x8*)
                        &B_lds[cur][(16 * (2 * h + j2) + lm) * 128 +
                                    (((c * 4 + quad) ^ lm) * 8)];
            #pragma unroll
            for (int c = 0; c < 4; ++c)
                #pragma unroll
                for (int i = 0; i < 4; ++i)
                    #pragma unroll
                    for (int j2 = 0; j2 < 2; ++j2)
                        acc[i][2 * h + j2] = __builtin_amdgcn_mfma_f32_16x16x32_bf16(
                            af[i][c], bfr[j2][c], acc[i][2 * h + j2], 0, 0, 0);
        }

        // row-max update
        #pragma unroll
        for (int i = 0; i < 4; ++i)
            #pragma unroll
            for (int r = 0; r < 4; ++r) {
                float m01 = fmaxf(acc[i][0][r], acc[i][1][r]);
                float m23 = fmaxf(acc[i][2][r], acc[i][3][r]);
                rv[4 * i + r] = fmaxf(rv[4 * i + r], fmaxf(m01, m23));
            }

        // col-max: in-lane tree over quad's 16 rows + fire-and-forget
        // LDS atomicMax (combines quads AND waves; no shfl chain)
        #pragma unroll
        for (int j = 0; j < 4; ++j) {
            float t0 = fmaxf(fmaxf(acc[0][j][0], acc[0][j][1]),
                             fmaxf(acc[0][j][2], acc[0][j][3]));
            float t1 = fmaxf(fmaxf(acc[1][j][0], acc[1][j][1]),
                             fmaxf(acc[1][j][2], acc[1][j][3]));
            float t2 = fmaxf(fmaxf(acc[2][j][0], acc[2][j][1]),
                             fmaxf(acc[2][j][2], acc[2][j][3]));
            float t3 = fmaxf(fmaxf(acc[3][j][0], acc[3][j][1]),
                             fmaxf(acc[3][j][2], acc[3][j][3]));
            float cv = fmaxf(fmaxf(t0, t1), fmaxf(t2, t3));
            atomicMax(&colmax_u[it * 64 + 16 * j + lm][quad], fkey(cv));
        }

        if (it < 15) STAGE_WRITE(q, cur ^ 1);   // convert + ds_write late

        __syncthreads();   // tile it+1 staged; buf cur free for it+2
    }

    // row maxes: butterfly across the 16 lane-cols; waves own disjoint rows
    #pragma unroll
    for (int s = 1; s < 16; s <<= 1)
        #pragma unroll
        for (int v = 0; v < 16; ++v)
            rv[v] = fmaxf(rv[v], __shfl_xor(rv[v], s, 64));
    if (lm == 0) {
        #pragma unroll
        for (int v = 0; v < 16; ++v)
            rowpart[((size_t)panel * B_ + b) * N_ + row0 + wrow +
                    16 * (v >> 2) + 4 * quad + (v & 3)] = rv[v];
    }

    // final loop barrier already ordered the last colmax atomics

    // flush col partials: 4 cols/thread, decode keys, float4 store
    {
        const int c0 = tid * 4;
        float cout[4];
        #pragma unroll
        for (int cc = 0; cc < 4; ++cc) {
            uint4 q = *(const uint4*)&colmax_u[c0 + cc][0];
            unsigned k = max(max(q.x, q.y), max(q.z, q.w));
            cout[cc] = funkey(k);
        }
        *(float4*)&colpart[((size_t)x * B_ + b) * M_ + (size_t)panel * 1024 + c0] =
            *(float4*)cout;
    }
}

// ---------------------------------------------------------------------------
// Reduce: 64 blocks (8 per batch). rows: max-e over 4 panel partials;
// cols: max-e over 16 row-block partials; d^2 = max(-2e, 0); sqrt-mean.
// ---------------------------------------------------------------------------
__global__ __launch_bounds__(256) void hausdorff_reduce(
    const float* __restrict__ rowpart, const float* __restrict__ colpart,
    float* __restrict__ out) {
    __shared__ float ws4[4];
    const int b    = blockIdx.x >> 3;
    const int part = blockIdx.x & 7;
    const int base = part * 512;
    float s = 0.f;
    for (int i = base + (int)threadIdx.x; i < base + 512; i += 256) {
        float ra = fmaxf(rowpart[((size_t)0 * B_ + b) * N_ + i],
                         rowpart[((size_t)1 * B_ + b) * N_ + i]);
        float rb = fmaxf(rowpart[((size_t)2 * B_ + b) * N_ + i],
                         rowpart[((size_t)3 * B_ + b) * N_ + i]);
        float rm = fmaxf(ra, rb);
        float ca = -1e30f, cb = -1e30f;
        #pragma unroll
        for (int xx = 0; xx < 16; xx += 2) {
            ca = fmaxf(ca, colpart[((size_t)xx * B_ + b) * M_ + i]);
            cb = fmaxf(cb, colpart[((size_t)(xx + 1) * B_ + b) * M_ + i]);
        }
        float cm = fmaxf(ca, cb);
        s += sqrtf(fmaxf(-2.f * rm, 0.f)) * (1.f / N_)
           + sqrtf(fmaxf(-2.f * cm, 0.f)) * (1.f / M_);
    }
    #pragma unroll
    for (int off = 32; off > 0; off >>= 1) s += __shfl_down(s, off, 64);
    if ((threadIdx.x & 63) == 0) ws4[threadIdx.x >> 6] = s;
    __syncthreads();
    if (threadIdx.x == 0)
        atomicAdd(&out[b], ws4[0] + ws4[1] + ws4[2] + ws4[3]);
}

extern "C" void kernel_launch(void* const* d_in, const int* in_sizes, int n_in,
                              void* d_out, int out_size, void* d_ws, size_t ws_size,
                              hipStream_t stream) {
    const float* s1 = (const float*)d_in[0];
    const float* s2 = (const float*)d_in[1];
    float* out = (float*)d_out;

    // ws: rowpart[4][B][N] | colpart[16][B][M]   (2.5 MB total)
    float* rowpart = (float*)d_ws;
    float* colpart = rowpart + (size_t)4 * B_ * N_;

    dim3 grid(N_ / 256, M_ / 1024, B_);
    hausdorff_fused<<<grid, 256, 0, stream>>>(s1, s2, rowpart, colpart, out);

    hausdorff_reduce<<<B_ * 8, 256, 0, stream>>>(rowpart, colpart, out);
}